// Round 9
// baseline (143.046 us; speedup 1.0000x reference)
//
#include <hip/hip_runtime.h>
#include <stdint.h>

// DVH global loss, MI355X.
// B=4 batches, N=2^21 voxels/batch, 500 bins over [0,75].
// loss = mean_{b,j} ( suffix_sum_{k>j}(hist_p[b]-hist_g[b])[k] / (maskcount_b+1e-6) )^2
// Only the DIFFERENCE histogram matters: d[i] = hist_p[i] - hist_g[i] (exact in ints).
//
// R1: device fence -> per-wave L2 writeback -> 201 us. Reverted.
// R2: fence-free last-block protocol, 512x1024, atomic drain -> 41.5 us kernel.
// R3: 4096x256 -> 117 us: drain atomics scale with block count.
// R4: per-block partial stores -> 1 MB single-block merge tail. Reverted.
// R5: 8-replica drain -> neutral. Main phase ~40 us.
// R6/R7/R8: three escalating attempts to force load MLP (sched_barrier,
//     asm keep-alives, full inline-asm counted-vmcnt pipeline). R8 provably
//     owned issue order -> time IDENTICAL to serial R2 (42.2 vs 41.6).
//     CONCLUSION: throughput-bound, not latency-bound. Latency theory dead.
// R9: ABLATION ROUND. Co-dispatch a pure delivery probe (same grid, same
//     12-load pattern, FMA + asm sink, no stores) before the unchanged R8
//     kernel. Probe duration = true delivery floor on poison-flushed caches.
//     Side effect: probe warms L3 with all 100 MB -> fused kernel's delta
//     vs 42 us measures its delivery-sensitivity. Decision matrix:
//       probe 13-20 us -> compute/DS-bound -> attack histogram pipeline next.
//       probe 35-45 us -> 3-stream pattern caps ~2.4 TB/s -> at roofline.

#define NBINS 500
#define NHIST 501          // searchsorted index c in [0,500]; c>=1 for d>=0
#define BATCH 4
#define NPB (1 << 21)      // elements per batch
#define VPB (NPB / 4)      // float4 per batch
#define THREADS 1024
#define BLOCKS_PER_BATCH 128
#define STRIDE (BLOCKS_PER_BATCH * THREADS)   // 131072 float4s; VPB/STRIDE == 4
#define TOTAL_BLOCKS (BLOCKS_PER_BATCH * BATCH)   // 512
#define REPS 8             // replica histograms per batch

// workspace layout (int32):
//   replica hists : [(b*REPS + r)*512 + i], i<512, r<8, b<4   (16384 ints)
//   maskcount     : [16384 + b]
//   done ctr      : [16388]
#define HIST_INTS (BATCH * REPS * 512)
#define MC_OFF HIST_INTS
#define CTR_OFF (HIST_INTS + 4)
#define ZERO_INTS (HIST_INTS + 8)

__device__ __forceinline__ int bin_of(float d) {
    // c = # of fp32 bins k*STEP that are <= d  (jnp.linspace(0,75,500),
    // searchsorted side='right'); d >= 0 guaranteed.
    const float STEP = 75.0f / 499.0f;
    const float INV  = 499.0f / 75.0f;
    int k = (int)(d * INV);
    if (k > 499) k = 499;
    if ((float)k * STEP > d) --k;
    else if (k < 499 && (float)(k + 1) * STEP <= d) ++k;
    if ((float)k * STEP > d) --k;   // safety second pass (k>=0 since bins[0]=0<=d)
    return k + 1;                   // in [1,500]
}

// ---------------- delivery-floor probe (no side effects) ----------------
// Identical grid/geometry/addresses to the fused kernel's load phase.
// Minimal VALU, results sunk via asm so loads can't be eliminated.
__global__ __launch_bounds__(THREADS) void delivery_probe(
        const float4* __restrict__ dp, const float4* __restrict__ dg,
        const float4* __restrict__ dm) {
    const size_t base = (size_t)blockIdx.y * VPB + blockIdx.x * THREADS + threadIdx.x;
    float4 a = {0.f, 0.f, 0.f, 0.f};
    #pragma unroll
    for (int c = 0; c < 4; ++c) {
        const size_t o = base + (size_t)c * STRIDE;
        float4 m = dm[o], p = dp[o], g = dg[o];
        a.x += m.x + p.x + g.x;  a.y += m.y + p.y + g.y;
        a.z += m.z + p.z + g.z;  a.w += m.w + p.w + g.w;
    }
    asm volatile("" :: "v"(a.x), "v"(a.y), "v"(a.z), "v"(a.w));
}

// Inline-asm 16B load (R8, kept: known-good, equals R2 perf).
__device__ __forceinline__ float4 ldx4(const float4* __restrict__ sbase,
                                       unsigned voff) {
    float4 r;
    asm volatile("global_load_dwordx4 %0, %1, %2"
                 : "=&v"(r)
                 : "v"(voff), "s"(sbase));
    return r;
}

#define WAITSB(n) do { \
    asm volatile("s_waitcnt vmcnt(" #n ")" ::: "memory"); \
    __builtin_amdgcn_sched_barrier(0); \
} while (0)

__global__ __launch_bounds__(THREADS) void dvh_fused_kernel(
        const float4* __restrict__ dp, const float4* __restrict__ dg,
        const float4* __restrict__ dm, int* __restrict__ ws,
        float* __restrict__ out) {
    __shared__ int shd[512];
    __shared__ unsigned int smc;
    __shared__ int lastflag;
    __shared__ int wtot[2][8];
    __shared__ float facc[16];

    const int b = blockIdx.y;
    const int t = threadIdx.x;
    if (t < 512) shd[t] = 0;
    if (t == 0) smc = 0u;
    __syncthreads();

    const unsigned e0 = (unsigned)(b * VPB + blockIdx.x * THREADS + t);
    const unsigned o0 = e0 * 16u;
    const unsigned o1 = o0 + (unsigned)STRIDE * 16u;
    const unsigned o2 = o1 + (unsigned)STRIDE * 16u;
    const unsigned o3 = o2 + (unsigned)STRIDE * 16u;

    float4 mA = ldx4(dm, o0); float4 pA = ldx4(dp, o0); float4 gA = ldx4(dg, o0);
    float4 mB = ldx4(dm, o1); float4 pB = ldx4(dp, o1); float4 gB = ldx4(dg, o1);
    float4 mC = ldx4(dm, o2); float4 pC = ldx4(dp, o2); float4 gC = ldx4(dg, o2);

    unsigned int myc = 0;
#define DO(mm, pp, gg) \
    if (mm != 0.0f) { atomicAdd(&shd[bin_of(pp)], 1); atomicAdd(&shd[bin_of(gg)], -1); ++myc; }
#define PROC(MM, PP, GG) \
    DO(MM.x, PP.x, GG.x) DO(MM.y, PP.y, GG.y) DO(MM.z, PP.z, GG.z) DO(MM.w, PP.w, GG.w)

    WAITSB(6);
    PROC(mA, pA, gA)
    float4 mD = ldx4(dm, o3); float4 pD = ldx4(dp, o3); float4 gD = ldx4(dg, o3);
    WAITSB(6);
    PROC(mB, pB, gB)
    WAITSB(3);
    PROC(mC, pC, gC)
    WAITSB(0);
    PROC(mD, pD, gD)
#undef PROC
#undef DO

    if (myc) atomicAdd(&smc, myc);
    __syncthreads();

    // Drain into one of 8 replica histograms (R5-verified).
    {
        const int rep = blockIdx.x & (REPS - 1);
        int* dst = &ws[(b * REPS + rep) * 512];
        if (t < 512) {
            int v = shd[t];
            if (v) atomicAdd(&dst[t], v);
        }
    }
    if (t == 0 && smc) atomicAdd((unsigned int*)&ws[MC_OFF + b], smc);

    // ---- last-arriving-block protocol (fence-free; verified R2/R4/R5) ----
    asm volatile("s_waitcnt vmcnt(0)" ::: "memory");
    __syncthreads();
    if (t == 0) {
        unsigned int old = atomicAdd((unsigned int*)&ws[CTR_OFF], 1u);
        lastflag = (old == TOTAL_BLOCKS - 1) ? 1 : 0;
    }
    __syncthreads();
    if (!lastflag) return;

    // Last block: merge 8 replicas per batch (64 KB), scan, suffix, square.
    const int lane = t & 63;
    const int w = t >> 6;
    const int h = t >> 9;
    const int j = t & 511;
    const int wl = (t >> 6) & 7;
    float acc = 0.0f;

    #pragma unroll
    for (int bi = 0; bi < 2; ++bi) {
        const int bb = h * 2 + bi;
        int s = 0;
        const int pb = (bb * REPS) * 512 + j;
        #pragma unroll
        for (int r = 0; r < REPS; ++r) {
            s += __hip_atomic_load(&ws[pb + r * 512],
                                   __ATOMIC_RELAXED, __HIP_MEMORY_SCOPE_AGENT);
        }
        int v = s;
        #pragma unroll
        for (int off = 1; off < 64; off <<= 1) {
            int n = __shfl_up(v, off, 64);
            if (lane >= off) v += n;
        }
        if (lane == 63) wtot[h][wl] = v;
        __syncthreads();
        int offset = 0, total = 0;
        #pragma unroll
        for (int i = 0; i < 8; ++i) {
            int x = wtot[h][i];
            total += x;
            if (i < wl) offset += x;
        }
        const int prefix = v + offset;
        const unsigned int mc = __hip_atomic_load(
            (unsigned int*)&ws[MC_OFF + bb], __ATOMIC_RELAXED,
            __HIP_MEMORY_SCOPE_AGENT);
        const float denom = (float)mc + 1e-6f;
        if (j < NBINS) {
            const float diff = (float)(total - prefix) / denom;
            acc += diff * diff;
        }
        __syncthreads();
    }

    #pragma unroll
    for (int off = 32; off > 0; off >>= 1) acc += __shfl_down(acc, off, 64);
    if (lane == 0) facc[w] = acc;
    __syncthreads();
    if (t == 0) {
        float ssum = 0.0f;
        #pragma unroll
        for (int i = 0; i < 16; ++i) ssum += facc[i];
        out[0] = ssum * (1.0f / (BATCH * NBINS));
    }
}

extern "C" void kernel_launch(void* const* d_in, const int* in_sizes, int n_in,
                              void* d_out, int out_size, void* d_ws, size_t ws_size,
                              hipStream_t stream) {
    const float4* dp = (const float4*)d_in[0];   // d_pred
    const float4* dg = (const float4*)d_in[1];   // d_gt
    const float4* dm = (const float4*)d_in[2];   // mask
    int* ws = (int*)d_ws;

    hipMemsetAsync(ws, 0, ZERO_INTS * sizeof(int), stream);

    dim3 grid(BLOCKS_PER_BATCH, BATCH);
    // Probe first: measures cold-cache delivery floor; warms L3 for fused.
    delivery_probe<<<grid, dim3(THREADS), 0, stream>>>(dp, dg, dm);
    dvh_fused_kernel<<<grid, dim3(THREADS), 0, stream>>>(dp, dg, dm, ws, (float*)d_out);
}

// Round 10
// 126.300 us; speedup vs baseline: 1.1326x; 1.1326x over previous
//
#include <hip/hip_runtime.h>
#include <stdint.h>

// DVH global loss, MI355X.
// B=4 batches, N=2^21 voxels/batch, 500 bins over [0,75].
// loss = mean_{b,j} ( suffix_sum_{k>j}(hist_p[b]-hist_g[b])[k] / (maskcount_b+1e-6) )^2
// Only the DIFFERENCE histogram matters: d[i] = hist_p[i] - hist_g[i] (exact in ints).
//
// R1: device fence -> per-wave L2 writeback -> 201 us. Reverted.
// R2: fence-free last-block protocol, 512x1024, atomic drain -> 41.5 us kernel.
// R3: 4096x256 -> 117 us: global drain atomics scale with block count.
// R4: per-block partial stores -> 1 MB single-block merge tail. Reverted.
// R5: 8-replica drain -> neutral. Main phase ~40 us.
// R6/R7/R8: forced load MLP (sched_barrier / keep-alives / full asm
//     counted-vmcnt pipeline). R8 owned issue order -> identical to serial
//     R2. Latency theory dead: throughput/issue-bound, not latency-bound.
// R9: delivery probe + warm fused = ~60 us combined; split ambiguous, but
//     bounded: either delivery caps ~2.6 TB/s cold, or fused burns ~40 us
//     independent of memory. Unattributed ~25 us points at DIVERGENCE:
//     30% random mask => P(wave skips an element body) ~ 0.7^64 ~ 0 =>
//     all 16 per-thread branches execute FULL-WAVE (19/64 lanes useful)
//     + 16x exec-mask save/branch/restore churn.
// R10: branchless full-lane inner loop. mask is exactly 0.0/1.0 =>
//     inc = (int)mm (one v_cvt); LDS atomics unconditional with +/-inc
//     (inc=0 adds are mathematical no-ops -> bit-identical result).
//     bin_of untouched (verified exact). Single-variable A/B on compute.

#define NBINS 500
#define NHIST 501          // searchsorted index c in [0,500]; c>=1 for d>=0
#define BATCH 4
#define NPB (1 << 21)      // elements per batch
#define VPB (NPB / 4)      // float4 per batch
#define THREADS 1024
#define BLOCKS_PER_BATCH 128
#define STRIDE (BLOCKS_PER_BATCH * THREADS)   // 131072 float4s; VPB/STRIDE == 4
#define TOTAL_BLOCKS (BLOCKS_PER_BATCH * BATCH)   // 512
#define REPS 8             // replica histograms per batch

// workspace layout (int32):
//   replica hists : [(b*REPS + r)*512 + i], i<512, r<8, b<4   (16384 ints)
//   maskcount     : [16384 + b]
//   done ctr      : [16388]
#define HIST_INTS (BATCH * REPS * 512)
#define MC_OFF HIST_INTS
#define CTR_OFF (HIST_INTS + 4)
#define ZERO_INTS (HIST_INTS + 8)

__device__ __forceinline__ int bin_of(float d) {
    // c = # of fp32 bins k*STEP that are <= d  (jnp.linspace(0,75,500),
    // searchsorted side='right'); d >= 0 guaranteed. VERIFIED EXACT - do not touch.
    const float STEP = 75.0f / 499.0f;
    const float INV  = 499.0f / 75.0f;
    int k = (int)(d * INV);
    if (k > 499) k = 499;
    if ((float)k * STEP > d) --k;
    else if (k < 499 && (float)(k + 1) * STEP <= d) ++k;
    if ((float)k * STEP > d) --k;   // safety second pass (k>=0 since bins[0]=0<=d)
    return k + 1;                   // in [1,500]
}

// Inline-asm 16B load (R8, kept: known-equal to HIP loads, keeps the load
// shape fixed while compute changes -> clean attribution).
__device__ __forceinline__ float4 ldx4(const float4* __restrict__ sbase,
                                       unsigned voff) {
    float4 r;
    asm volatile("global_load_dwordx4 %0, %1, %2"
                 : "=&v"(r)
                 : "v"(voff), "s"(sbase));
    return r;
}

#define WAITSB(n) do { \
    asm volatile("s_waitcnt vmcnt(" #n ")" ::: "memory"); \
    __builtin_amdgcn_sched_barrier(0); \
} while (0)

__global__ __launch_bounds__(THREADS) void dvh_fused_kernel(
        const float4* __restrict__ dp, const float4* __restrict__ dg,
        const float4* __restrict__ dm, int* __restrict__ ws,
        float* __restrict__ out) {
    __shared__ int shd[512];
    __shared__ unsigned int smc;
    __shared__ int lastflag;
    __shared__ int wtot[2][8];
    __shared__ float facc[16];

    const int b = blockIdx.y;
    const int t = threadIdx.x;
    if (t < 512) shd[t] = 0;
    if (t == 0) smc = 0u;
    __syncthreads();

    const unsigned e0 = (unsigned)(b * VPB + blockIdx.x * THREADS + t);
    const unsigned o0 = e0 * 16u;
    const unsigned o1 = o0 + (unsigned)STRIDE * 16u;
    const unsigned o2 = o1 + (unsigned)STRIDE * 16u;
    const unsigned o3 = o2 + (unsigned)STRIDE * 16u;

    float4 mA = ldx4(dm, o0); float4 pA = ldx4(dp, o0); float4 gA = ldx4(dg, o0);
    float4 mB = ldx4(dm, o1); float4 pB = ldx4(dp, o1); float4 gB = ldx4(dg, o1);
    float4 mC = ldx4(dm, o2); float4 pC = ldx4(dp, o2); float4 gC = ldx4(dg, o2);

    unsigned int myc = 0;
    // Branchless, full-lane: mask is exactly 0.0f or 1.0f -> inc in {0,1}.
    // atomicAdd of 0 is a mathematical no-op -> result bit-identical to the
    // branchy version; removes 16 divergent branches + exec-mask churn.
#define DO(mm, pp, gg) { \
    const int inc = (int)(mm); \
    myc += (unsigned)inc; \
    atomicAdd(&shd[bin_of(pp)],  inc); \
    atomicAdd(&shd[bin_of(gg)], -inc); }
#define PROC(MM, PP, GG) \
    DO(MM.x, PP.x, GG.x) DO(MM.y, PP.y, GG.y) DO(MM.z, PP.z, GG.z) DO(MM.w, PP.w, GG.w)

    WAITSB(6);               // chunk A landed; B,C in flight
    PROC(mA, pA, gA)
    float4 mD = ldx4(dm, o3); float4 pD = ldx4(dp, o3); float4 gD = ldx4(dg, o3);
    WAITSB(6);               // chunk B landed; C,D in flight
    PROC(mB, pB, gB)
    WAITSB(3);               // chunk C landed; D in flight
    PROC(mC, pC, gC)
    WAITSB(0);               // chunk D landed
    PROC(mD, pD, gD)
#undef PROC
#undef DO

    if (myc) atomicAdd(&smc, myc);
    __syncthreads();

    // Drain into one of 8 replica histograms (R5-verified).
    {
        const int rep = blockIdx.x & (REPS - 1);
        int* dst = &ws[(b * REPS + rep) * 512];
        if (t < 512) {
            int v = shd[t];
            if (v) atomicAdd(&dst[t], v);
        }
    }
    if (t == 0 && smc) atomicAdd((unsigned int*)&ws[MC_OFF + b], smc);

    // ---- last-arriving-block protocol (fence-free; verified R2/R4/R5) ----
    asm volatile("s_waitcnt vmcnt(0)" ::: "memory");
    __syncthreads();
    if (t == 0) {
        unsigned int old = atomicAdd((unsigned int*)&ws[CTR_OFF], 1u);
        lastflag = (old == TOTAL_BLOCKS - 1) ? 1 : 0;
    }
    __syncthreads();
    if (!lastflag) return;

    // Last block: merge 8 replicas per batch (64 KB), scan, suffix, square.
    const int lane = t & 63;
    const int w = t >> 6;
    const int h = t >> 9;
    const int j = t & 511;
    const int wl = (t >> 6) & 7;
    float acc = 0.0f;

    #pragma unroll
    for (int bi = 0; bi < 2; ++bi) {
        const int bb = h * 2 + bi;
        int s = 0;
        const int pb = (bb * REPS) * 512 + j;
        #pragma unroll
        for (int r = 0; r < REPS; ++r) {
            s += __hip_atomic_load(&ws[pb + r * 512],
                                   __ATOMIC_RELAXED, __HIP_MEMORY_SCOPE_AGENT);
        }
        int v = s;
        #pragma unroll
        for (int off = 1; off < 64; off <<= 1) {
            int n = __shfl_up(v, off, 64);
            if (lane >= off) v += n;
        }
        if (lane == 63) wtot[h][wl] = v;
        __syncthreads();
        int offset = 0, total = 0;
        #pragma unroll
        for (int i = 0; i < 8; ++i) {
            int x = wtot[h][i];
            total += x;
            if (i < wl) offset += x;
        }
        const int prefix = v + offset;
        const unsigned int mc = __hip_atomic_load(
            (unsigned int*)&ws[MC_OFF + bb], __ATOMIC_RELAXED,
            __HIP_MEMORY_SCOPE_AGENT);
        const float denom = (float)mc + 1e-6f;
        if (j < NBINS) {
            const float diff = (float)(total - prefix) / denom;
            acc += diff * diff;
        }
        __syncthreads();
    }

    #pragma unroll
    for (int off = 32; off > 0; off >>= 1) acc += __shfl_down(acc, off, 64);
    if (lane == 0) facc[w] = acc;
    __syncthreads();
    if (t == 0) {
        float ssum = 0.0f;
        #pragma unroll
        for (int i = 0; i < 16; ++i) ssum += facc[i];
        out[0] = ssum * (1.0f / (BATCH * NBINS));
    }
}

extern "C" void kernel_launch(void* const* d_in, const int* in_sizes, int n_in,
                              void* d_out, int out_size, void* d_ws, size_t ws_size,
                              hipStream_t stream) {
    const float4* dp = (const float4*)d_in[0];   // d_pred
    const float4* dg = (const float4*)d_in[1];   // d_gt
    const float4* dm = (const float4*)d_in[2];   // mask
    int* ws = (int*)d_ws;

    hipMemsetAsync(ws, 0, ZERO_INTS * sizeof(int), stream);

    dim3 grid(BLOCKS_PER_BATCH, BATCH);
    dvh_fused_kernel<<<grid, dim3(THREADS), 0, stream>>>(dp, dg, dm, ws, (float*)d_out);
}